// Round 1
// baseline (371.592 us; speedup 1.0000x reference)
//
#include <hip/hip_runtime.h>
#include <hip/hip_bf16.h>
#include <stdint.h>

typedef __attribute__((ext_vector_type(8))) short short8;
typedef __attribute__((ext_vector_type(4))) float f32x4;

#define CH 32
#define NC 256   /* 8192 / CH */

__device__ __forceinline__ unsigned short f2bf(float f) {
  union { float f; unsigned u; } x; x.f = f;
  unsigned u = x.u;
  u = (u + 0x7fffu + ((u >> 16) & 1u)) >> 16;
  return (unsigned short)u;
}
__device__ __forceinline__ float bf2f(unsigned short h) {
  union { unsigned u; float f; } x; x.u = ((unsigned)h) << 16;
  return x.f;
}

// storage helpers: a/v arrays can be f32 or bf16 depending on ws budget
__device__ __forceinline__ void store1(float* p, float v) { *p = v; }
__device__ __forceinline__ void store1(unsigned short* p, float v) { *p = f2bf(v); }
__device__ __forceinline__ float4 ld4(const float* p, size_t idx4) {
  return reinterpret_cast<const float4*>(p)[idx4];
}
__device__ __forceinline__ float4 ld4(const unsigned short* p, size_t idx4) {
  ushort4 u = reinterpret_cast<const ushort4*>(p)[idx4];
  return make_float4(bf2f(u.x), bf2f(u.y), bf2f(u.z), bf2f(u.w));
}

#define GLOAD_LDS16(gptr, lptr) \
  __builtin_amdgcn_global_load_lds((const __attribute__((address_space(1))) void*)(gptr), \
                                   (__attribute__((address_space(3))) void*)(lptr), 16, 0, 0)

// ---------------- f32 -> bf16 convert (vectorized) ----------------
__global__ void k_f32_to_bf16(const float* __restrict__ src, unsigned short* __restrict__ dst, int n4) {
  int i = blockIdx.x * blockDim.x + threadIdx.x;
  if (i >= n4) return;
  float4 f = reinterpret_cast<const float4*>(src)[i];
  ushort4 o = make_ushort4(f2bf(f.x), f2bf(f.y), f2bf(f.z), f2bf(f.w));
  reinterpret_cast<ushort4*>(dst)[i] = o;
}

// ---------------- GEMM1: hg = X @ W_hg^T, dual-B (h and gate halves) ---------
// Xb: 32768x512 bf16, Wb: 2048x512 bf16. Block computes 128(m) x 128(i) of both
// the h half (rows i0..i0+127 of W) and gate half (rows 1024+i0..). Epilogue
// fuses the MinGRU nonlinearity and writes a,v in (B*S, Di) layout.
template <typename TS>
__global__ __launch_bounds__(256, 2) void k_gemm1(
    const unsigned short* __restrict__ Xb,
    const unsigned short* __restrict__ Wb,
    TS* __restrict__ aArr, TS* __restrict__ vArr)
{
  __shared__ unsigned short As[128 * 64];
  __shared__ unsigned short Bs0[128 * 64];
  __shared__ unsigned short Bs1[128 * 64];

  const int m0 = blockIdx.y * 128;
  const int i0 = blockIdx.x * 128;
  const int tid = threadIdx.x;
  const int lane = tid & 63;
  const int wave = tid >> 6;
  const int wm = (wave >> 1) * 64;
  const int wn = (wave & 1) * 64;
  const int srow = tid >> 3;         // 0..31
  const int scol = (tid & 7) * 8;    // element col in [0,64)

  f32x4 acc0[4][4], acc1[4][4];
#pragma unroll
  for (int f = 0; f < 4; ++f)
#pragma unroll
    for (int g = 0; g < 4; ++g) {
      acc0[f][g] = f32x4{0.f, 0.f, 0.f, 0.f};
      acc1[f][g] = f32x4{0.f, 0.f, 0.f, 0.f};
    }

  for (int k0 = 0; k0 < 512; k0 += 64) {
    __syncthreads();   // all waves done reading previous tile
#pragma unroll
    for (int j = 0; j < 4; ++j) {
      int row = j * 32 + srow;
      GLOAD_LDS16(Xb + (size_t)(m0 + row) * 512 + k0 + scol, As + row * 64 + scol);
    }
#pragma unroll
    for (int j = 0; j < 4; ++j) {
      int row = j * 32 + srow;
      GLOAD_LDS16(Wb + (size_t)(i0 + row) * 512 + k0 + scol, Bs0 + row * 64 + scol);
    }
#pragma unroll
    for (int j = 0; j < 4; ++j) {
      int row = j * 32 + srow;
      GLOAD_LDS16(Wb + (size_t)(1024 + i0 + row) * 512 + k0 + scol, Bs1 + row * 64 + scol);
    }
    __syncthreads();   // compiler drains vmcnt before barrier -> LDS ready

#pragma unroll
    for (int kk = 0; kk < 2; ++kk) {
      const int kof = kk * 32 + (lane >> 4) * 8;
      const int rl = lane & 15;
      short8 av[4], b0[4], b1[4];
#pragma unroll
      for (int f = 0; f < 4; ++f)
        av[f] = *(const short8*)(As + (wm + f * 16 + rl) * 64 + kof);
#pragma unroll
      for (int g = 0; g < 4; ++g) {
        b0[g] = *(const short8*)(Bs0 + (wn + g * 16 + rl) * 64 + kof);
        b1[g] = *(const short8*)(Bs1 + (wn + g * 16 + rl) * 64 + kof);
      }
#pragma unroll
      for (int f = 0; f < 4; ++f)
#pragma unroll
        for (int g = 0; g < 4; ++g) {
          acc0[f][g] = __builtin_amdgcn_mfma_f32_16x16x32_bf16(av[f], b0[g], acc0[f][g], 0, 0, 0);
          acc1[f][g] = __builtin_amdgcn_mfma_f32_16x16x32_bf16(av[f], b1[g], acc1[f][g], 0, 0, 0);
        }
    }
  }

  // epilogue: C/D layout col = lane&15, row = (lane>>4)*4 + reg
  const int rl = lane & 15;
  const int rr = (lane >> 4) * 4;
#pragma unroll
  for (int f = 0; f < 4; ++f) {
#pragma unroll
    for (int g = 0; g < 4; ++g) {
#pragma unroll
      for (int r = 0; r < 4; ++r) {
        int m = m0 + wm + f * 16 + rr + r;
        int i = i0 + wn + g * 16 + rl;
        float h    = acc0[f][g][r];
        float gate = acc1[f][g][r];
        float e  = __expf(gate);
        float ac = 1.f / (1.f + e);          // sigmoid(-gate) = exp(-softplus(gate))
        float z  = e / (1.f + e);            // sigmoid(gate)
        float gg = (h >= 0.f) ? (h + 0.5f) : (1.f / (1.f + __expf(-h)));
        size_t off = (size_t)m * 1024 + i;
        store1(aArr + off, ac);
        store1(vArr + off, z * gg);
      }
    }
  }
}

// ---------------- scan phase A: per-chunk (A_prod, V) reduction ----------------
template <typename TS>
__global__ void k_scanA(const TS* __restrict__ aArr, const TS* __restrict__ vArr,
                        float* __restrict__ Acar, float* __restrict__ Vcar)
{
  int c = blockIdx.x & (NC - 1);
  int b = blockIdx.x >> 8;
  size_t base4 = (((size_t)b * 8192 + (size_t)c * CH) * 1024) / 4 + threadIdx.x;
  float4 A = make_float4(1.f, 1.f, 1.f, 1.f);
  float4 V = make_float4(0.f, 0.f, 0.f, 0.f);
#pragma unroll 4
  for (int t = 0; t < CH; ++t) {
    float4 at = ld4(aArr, base4 + (size_t)t * 256);
    float4 vt = ld4(vArr, base4 + (size_t)t * 256);
    V.x = fmaf(at.x, V.x, vt.x); V.y = fmaf(at.y, V.y, vt.y);
    V.z = fmaf(at.z, V.z, vt.z); V.w = fmaf(at.w, V.w, vt.w);
    A.x *= at.x; A.y *= at.y; A.z *= at.z; A.w *= at.w;
  }
  size_t co = (((size_t)b * NC + c) * 1024) / 4 + threadIdx.x;
  reinterpret_cast<float4*>(Acar)[co] = A;
  reinterpret_cast<float4*>(Vcar)[co] = V;
}

// ---------------- scan phase B: sequential carry combine over chunks ----------
__global__ void k_scanB(const float* __restrict__ hidden,
                        const float* __restrict__ Acar, const float* __restrict__ Vcar,
                        float* __restrict__ Hstart)
{
  int t = blockIdx.x * blockDim.x + threadIdx.x;  // 0..4095
  int b = t >> 10, i = t & 1023;
  float H = hidden[(size_t)b * 1024 + i];
  for (int c = 0; c < NC; ++c) {
    size_t o = ((size_t)b * NC + c) * 1024 + i;
    Hstart[o] = H;
    H = fmaf(Acar[o], H, Vcar[o]);
  }
}

// ---------------- scan phase C: re-scan with correct H, emit h_all (bf16) -----
template <typename TS>
__global__ void k_scanC(const TS* __restrict__ aArr, const TS* __restrict__ vArr,
                        const float* __restrict__ Hstart,
                        unsigned short* __restrict__ hAll, float* __restrict__ nextH)
{
  int c = blockIdx.x & (NC - 1);
  int b = blockIdx.x >> 8;
  size_t base4 = (((size_t)b * 8192 + (size_t)c * CH) * 1024) / 4 + threadIdx.x;
  size_t ho = (((size_t)b * NC + c) * 1024) / 4 + threadIdx.x;
  float4 H = reinterpret_cast<const float4*>(Hstart)[ho];
#pragma unroll 4
  for (int t = 0; t < CH; ++t) {
    float4 at = ld4(aArr, base4 + (size_t)t * 256);
    float4 vt = ld4(vArr, base4 + (size_t)t * 256);
    H.x = fmaf(at.x, H.x, vt.x); H.y = fmaf(at.y, H.y, vt.y);
    H.z = fmaf(at.z, H.z, vt.z); H.w = fmaf(at.w, H.w, vt.w);
    ushort4 o = make_ushort4(f2bf(H.x), f2bf(H.y), f2bf(H.z), f2bf(H.w));
    reinterpret_cast<ushort4*>(hAll)[base4 + (size_t)t * 256] = o;
  }
  if (c == NC - 1)
    reinterpret_cast<float4*>(nextH)[(size_t)b * 256 + threadIdx.x] = H;
}

// ---------------- GEMM2: out = h_all @ W_out^T ----------------
__global__ __launch_bounds__(256, 2) void k_gemm2(
    const unsigned short* __restrict__ Ab,   // 32768 x 1024 bf16
    const unsigned short* __restrict__ Bb,   // 512 x 1024 bf16
    float* __restrict__ out)                 // 32768 x 512 f32
{
  __shared__ unsigned short As[128 * 64];
  __shared__ unsigned short Bs[128 * 64];

  const int m0 = blockIdx.y * 128;
  const int n0 = blockIdx.x * 128;
  const int tid = threadIdx.x;
  const int lane = tid & 63;
  const int wave = tid >> 6;
  const int wm = (wave >> 1) * 64;
  const int wn = (wave & 1) * 64;
  const int srow = tid >> 3;
  const int scol = (tid & 7) * 8;

  f32x4 acc[4][4];
#pragma unroll
  for (int f = 0; f < 4; ++f)
#pragma unroll
    for (int g = 0; g < 4; ++g) acc[f][g] = f32x4{0.f, 0.f, 0.f, 0.f};

  for (int k0 = 0; k0 < 1024; k0 += 64) {
    __syncthreads();
#pragma unroll
    for (int j = 0; j < 4; ++j) {
      int row = j * 32 + srow;
      GLOAD_LDS16(Ab + (size_t)(m0 + row) * 1024 + k0 + scol, As + row * 64 + scol);
    }
#pragma unroll
    for (int j = 0; j < 4; ++j) {
      int row = j * 32 + srow;
      GLOAD_LDS16(Bb + (size_t)(n0 + row) * 1024 + k0 + scol, Bs + row * 64 + scol);
    }
    __syncthreads();

#pragma unroll
    for (int kk = 0; kk < 2; ++kk) {
      const int kof = kk * 32 + (lane >> 4) * 8;
      const int rl = lane & 15;
      short8 av[4], bv[4];
#pragma unroll
      for (int f = 0; f < 4; ++f)
        av[f] = *(const short8*)(As + (wm + f * 16 + rl) * 64 + kof);
#pragma unroll
      for (int g = 0; g < 4; ++g)
        bv[g] = *(const short8*)(Bs + (wn + g * 16 + rl) * 64 + kof);
#pragma unroll
      for (int f = 0; f < 4; ++f)
#pragma unroll
        for (int g = 0; g < 4; ++g)
          acc[f][g] = __builtin_amdgcn_mfma_f32_16x16x32_bf16(av[f], bv[g], acc[f][g], 0, 0, 0);
    }
  }

  const int rl = lane & 15;
  const int rr = (lane >> 4) * 4;
#pragma unroll
  for (int f = 0; f < 4; ++f)
#pragma unroll
    for (int g = 0; g < 4; ++g)
#pragma unroll
      for (int r = 0; r < 4; ++r) {
        int m = m0 + wm + f * 16 + rr + r;
        int n = n0 + wn + g * 16 + rl;
        out[(size_t)m * 512 + n] = acc[f][g][r];
      }
}

// ---------------- driver ----------------
template <typename TS>
static void run_pipeline(const float* X, const float* hidden, const float* W_hg,
                         const float* W_out, float* out, float* nextH,
                         unsigned short* Xb, unsigned short* Whgb, unsigned short* Woutb,
                         unsigned short* hAll, float* Acar, float* Vcar, float* Hstart,
                         TS* aArr, TS* vArr, hipStream_t stream)
{
  k_f32_to_bf16<<<16384, 256, 0, stream>>>(X, Xb, 16777216 / 4);
  k_f32_to_bf16<<<1024, 256, 0, stream>>>(W_hg, Whgb, 1048576 / 4);
  k_f32_to_bf16<<<512, 256, 0, stream>>>(W_out, Woutb, 524288 / 4);

  dim3 g1(8, 256);
  k_gemm1<TS><<<g1, 256, 0, stream>>>(Xb, Whgb, aArr, vArr);

  k_scanA<TS><<<4 * NC, 256, 0, stream>>>(aArr, vArr, Acar, Vcar);
  k_scanB<<<16, 256, 0, stream>>>(hidden, Acar, Vcar, Hstart);
  k_scanC<TS><<<4 * NC, 256, 0, stream>>>(aArr, vArr, Hstart, hAll, nextH);

  dim3 g2(4, 256);
  k_gemm2<<<g2, 256, 0, stream>>>(hAll, Woutb, out);
}

extern "C" void kernel_launch(void* const* d_in, const int* in_sizes, int n_in,
                              void* d_out, int out_size, void* d_ws, size_t ws_size,
                              hipStream_t stream) {
  const float* X      = (const float*)d_in[0];
  const float* hidden = (const float*)d_in[1];
  const float* W_hg   = (const float*)d_in[2];
  const float* W_out  = (const float*)d_in[3];

  float* out   = (float*)d_out;                    // (4,8192,512) f32
  float* nextH = out + (size_t)32768 * 512;        // (4,1,1024) f32

  char* ws = (char*)d_ws;
  size_t off = 0;
  auto alloc = [&](size_t bytes) -> void* {
    void* p = ws + off;
    off = (off + bytes + 255) & ~(size_t)255;
    return p;
  };
  unsigned short* Xb    = (unsigned short*)alloc(32768ULL * 512 * 2);
  unsigned short* Whgb  = (unsigned short*)alloc(2048ULL * 512 * 2);
  unsigned short* Woutb = (unsigned short*)alloc(512ULL * 1024 * 2);
  unsigned short* hAll  = (unsigned short*)alloc(32768ULL * 1024 * 2);
  float* Acar   = (float*)alloc(4ULL * NC * 1024 * 4);
  float* Vcar   = (float*)alloc(4ULL * NC * 1024 * 4);
  float* Hstart = (float*)alloc(4ULL * NC * 1024 * 4);

  const size_t fixed = off;
  const size_t need_f32 = fixed + 2ULL * 32768ULL * 1024 * 4 + 512;

  if (ws_size >= need_f32) {
    float* aArr = (float*)alloc(32768ULL * 1024 * 4);
    float* vArr = (float*)alloc(32768ULL * 1024 * 4);
    run_pipeline<float>(X, hidden, W_hg, W_out, out, nextH,
                        Xb, Whgb, Woutb, hAll, Acar, Vcar, Hstart, aArr, vArr, stream);
  } else {
    unsigned short* aArr = (unsigned short*)alloc(32768ULL * 1024 * 2);
    unsigned short* vArr = (unsigned short*)alloc(32768ULL * 1024 * 2);
    run_pipeline<unsigned short>(X, hidden, W_hg, W_out, out, nextH,
                                 Xb, Whgb, Woutb, hAll, Acar, Vcar, Hstart, aArr, vArr, stream);
  }
}